// Round 2
// baseline (770.677 us; speedup 1.0000x reference)
//
#include <hip/hip_runtime.h>

#define N_TOK 131072
#define DIM   256
#define KCB   1024

#define RT    128          // rows per block
#define KT    128          // codes per kt chunk
#define TAU   0.02f        // candidate margin; ~7x worst-case |dd' - dd_fp32| for fp16 plane
#define EMIT_CAP 4096
#define CB_SCALE 4096.0f   // exact pow2 pre-scale of codebook before fp16 (kills subnormals)
#define ACC_SCL  4.8828125e-4f   // 2.0f / 4096.0f, exact pow2: dv = zz - acc*ACC_SCL + cc

typedef __attribute__((ext_vector_type(8))) _Float16 f16x8;
typedef __attribute__((ext_vector_type(4))) float f32x4;

// async global->LDS, 16B per lane; LDS dest must be wave-uniform base + lane*16
__device__ __forceinline__ void gload_lds16(const short* g, short* l) {
  __builtin_amdgcn_global_load_lds(
      (const __attribute__((address_space(1))) void*)g,
      (__attribute__((address_space(3))) void*)l, 16, 0, 0);
}

// Bit-exact replica of numpy pairwise_sum over 128 floats of x*x.
__device__ __forceinline__ float np_sumsq_128(const float* __restrict__ p) {
#pragma clang fp contract(off)
  float4 a = *(const float4*)(p);
  float4 b = *(const float4*)(p + 4);
  float r0 = a.x * a.x, r1 = a.y * a.y, r2 = a.z * a.z, r3 = a.w * a.w;
  float r4 = b.x * b.x, r5 = b.y * b.y, r6 = b.z * b.z, r7 = b.w * b.w;
  for (int i = 8; i < 128; i += 8) {
    float4 c = *(const float4*)(p + i);
    float4 d = *(const float4*)(p + i + 4);
    r0 += c.x * c.x; r1 += c.y * c.y; r2 += c.z * c.z; r3 += c.w * c.w;
    r4 += d.x * d.x; r5 += d.y * d.y; r6 += d.z * d.z; r7 += d.w * d.w;
  }
  return ((r0 + r1) + (r2 + r3)) + ((r4 + r5) + (r6 + r7));
}

// K0a: ||c_k||^2 (bit-exact vs reference) + zero the fp64 loss accumulator.
__global__ void prep_cc(const float* __restrict__ cb, float* __restrict__ cc,
                        double* __restrict__ loss_acc) {
  int k = blockIdx.x * blockDim.x + threadIdx.x;
  if (k == 0) *loss_acc = 0.0;
  if (k < KCB) {
    const float* p = cb + (long)k * DIM;
    cc[k] = np_sumsq_128(p) + np_sumsq_128(p + 128);
  }
}

// K0b: codebook -> fp16 (scaled by 4096), in MFMA-fragment-major slice layout.
// short index o:  dl=o&7, k15=(o>>3)&15, qd=(o>>7)&3, dsl=(o>>9)&1,
//                 kg8=(o>>10)&7, p=(o>>13)&3, kt=(o>>15)&7
//   k = kt*128 + kg8*16 + k15,  d = (2p+dsl)*32 + qd*8 + dl
// Slice s = kt*4+p is a contiguous 16KB block -> linear global_load_lds staging,
// and every b-fragment ds_read_b128 is a linear conflict-free 1KB wave read.
__global__ void prep_h16(const float* __restrict__ cb, short* __restrict__ ch) {
  int o = blockIdx.x * blockDim.x + threadIdx.x;
  if (o < KCB * DIM) {
    int dl = o & 7, k15 = (o >> 3) & 15, qd = (o >> 7) & 3;
    int dsl = (o >> 9) & 1, kg8 = (o >> 10) & 7;
    int p = (o >> 13) & 3, kt = (o >> 15) & 7;
    int k = kt * 128 + kg8 * 16 + k15;
    int d = (2 * p + dsl) * 32 + qd * 8 + dl;
    float v = cb[k * DIM + d] * CB_SCALE;   // exact pow2 scale
    ((_Float16*)ch)[o] = (_Float16)v;       // RTNE
  }
}

// K1: single fp16 MFMA distance + candidate emission + exact fmaf-chain recheck.
// z fp16 fragments in registers (converted once); codebook double-buffered via
// global_load_lds, BK=64 per barrier, 3 blocks/CU.
__global__ __launch_bounds__(256, 3)
void argmin_kernel(const float* __restrict__ z, const float* __restrict__ cb,
                   const short* __restrict__ ch_g,
                   const float* __restrict__ cc_g, float* __restrict__ ids_f) {
  // [buf][8192 shorts = 16KB]: one 64-dim slice of 128 codes (fp16)
  __shared__ __align__(16) short cbuf[2][8192];
  __shared__ float zz_s[RT];
  __shared__ float zz_half[RT][2];
  __shared__ unsigned rowmin_s[RT];   // packed fp32 bits (positive -> monotonic)
  __shared__ int kmin_s[RT];
  __shared__ unsigned emit_s[EMIT_CAP];
  __shared__ int emit_cnt;

  const int t    = threadIdx.x;
  const int lane = t & 63;
  const int w    = t >> 6;       // wave 0..3, owns rows 32w..32w+31
  const int l15  = lane & 15;
  const int qd   = lane >> 4;    // quad 0..3
  const long rowbase = (long)blockIdx.x * RT;

  // ---- prologue: stage slice 0 into cbuf[0] (latency hidden under zz/A-prep) ----
#pragma unroll
  for (int j = 0; j < 4; ++j) {
    int off = w * 2048 + j * 512 + lane * 8;
    gload_lds16(ch_g + off, &cbuf[0][0] + off);
  }

  // ||z_row||^2, numpy order (bit-exact)
  {
    int r = t >> 1, h = t & 1;
    zz_half[r][h] = np_sumsq_128(z + (rowbase + r) * DIM + h * 128);
  }
  if (t < RT) { rowmin_s[t] = 0xFFFFFFFFu; kmin_s[t] = 0x7FFFFFFF; }
  if (t == 0) emit_cnt = 0;

  // ---- z A-fragments: load + fp16 convert ONCE, kept in VGPRs (64 VGPRs) ----
  // lane holds z[row = 32w+16m+l15][ds*32 + qd*8 .. +7]
  f16x8 a16[2][8];
  {
    const float* zp0 = z + (rowbase + 32 * w + l15) * (long)DIM + qd * 8;
#pragma unroll
    for (int m = 0; m < 2; ++m) {
      const float* zp = zp0 + m * 16 * DIM;
#pragma unroll
      for (int ds = 0; ds < 8; ++ds) {
        float4 v0 = *(const float4*)(zp + ds * 32);
        float4 v1 = *(const float4*)(zp + ds * 32 + 4);
        float f[8] = {v0.x, v0.y, v0.z, v0.w, v1.x, v1.y, v1.z, v1.w};
#pragma unroll
        for (int j = 0; j < 8; ++j) a16[m][ds][j] = (_Float16)f[j];  // RTNE
      }
    }
  }

  __syncthreads();   // slice 0 staged (barrier drains vmcnt), zz_half visible
  if (t < RT) zz_s[t] = zz_half[t][0] + zz_half[t][1];
  // zz_s visibility for epilogue: guaranteed by the per-slice barriers below

#pragma clang loop unroll(disable)
  for (int kt = 0; kt < 8; ++kt) {
    f32x4 acc[2][8];
#pragma unroll
    for (int m = 0; m < 2; ++m)
#pragma unroll
      for (int c = 0; c < 8; ++c) acc[m][c] = (f32x4){0.f, 0.f, 0.f, 0.f};

    // 4 slices of BK=64 per chunk; p unrolled so buffer parity (p&1) and
    // a16[m][2p+dsl] indices are compile-time (rule: no runtime vec indexing)
#pragma unroll
    for (int p = 0; p < 4; ++p) {
      int s = kt * 4 + p;
      // prefetch next slice into the other buffer BEFORE this slice's MFMAs
      if (s < 31) {
        const short* src = ch_g + (long)(s + 1) * 8192;
#pragma unroll
        for (int j = 0; j < 4; ++j) {
          int off = w * 2048 + j * 512 + lane * 8;
          gload_lds16(src + off, &cbuf[(p + 1) & 1][0] + off);
        }
      }
      // compute on cbuf[p&1]: 16 linear 1KB wave reads, 32 MFMAs per wave
#pragma unroll
      for (int dsl = 0; dsl < 2; ++dsl) {
#pragma unroll
        for (int c = 0; c < 8; ++c) {
          f16x8 b = *(const f16x8*)&cbuf[p & 1][c * 1024 + dsl * 512 + lane * 8];
          acc[0][c] = __builtin_amdgcn_mfma_f32_16x16x32_f16(a16[0][2 * p + dsl], b, acc[0][c], 0, 0, 0);
          acc[1][c] = __builtin_amdgcn_mfma_f32_16x16x32_f16(a16[1][2 * p + dsl], b, acc[1][c], 0, 0, 0);
        }
      }
      if (p < 3) __syncthreads();   // vmcnt(0)+barrier: next slice ready
    }

    // ---- kt epilogue: update per-row running min of dv ----
    // C/D layout: col = lane&15 (code), row = quad*4 + reg (within 16-tile)
    float ccv[8];
#pragma unroll
    for (int c = 0; c < 8; ++c) ccv[c] = cc_g[kt * KT + 16 * c + l15];
    float rmin[2][4];
#pragma unroll
    for (int m = 0; m < 2; ++m)
#pragma unroll
      for (int rg = 0; rg < 4; ++rg) {
        int row = 32 * w + 16 * m + 4 * qd + rg;
        float zz = zz_s[row];
        float mn = __builtin_inff();
#pragma unroll
        for (int c = 0; c < 8; ++c) {
          float dv = (zz - acc[m][c][rg] * ACC_SCL) + ccv[c];
          mn = fminf(mn, dv);
        }
        rmin[m][rg] = mn;
      }
#pragma unroll
    for (int off = 1; off < 16; off <<= 1)
#pragma unroll
      for (int m = 0; m < 2; ++m)
#pragma unroll
        for (int rg = 0; rg < 4; ++rg)
          rmin[m][rg] = fminf(rmin[m][rg], __shfl_xor(rmin[m][rg], off, 64));
    if (l15 == 0) {
#pragma unroll
      for (int m = 0; m < 2; ++m)
#pragma unroll
        for (int rg = 0; rg < 4; ++rg)
          atomicMin(&rowmin_s[32 * w + 16 * m + 4 * qd + rg], __float_as_uint(rmin[m][rg]));
    }
    __syncthreads();   // rowmin complete; also drains next-kt slice-0 stage
    // ---- emission: dv <= running_min + TAU (superset of exact-argmin+ties) ----
#pragma unroll
    for (int m = 0; m < 2; ++m)
#pragma unroll
      for (int rg = 0; rg < 4; ++rg) {
        int row = 32 * w + 16 * m + 4 * qd + rg;
        float th = __uint_as_float(rowmin_s[row]) + TAU;
        float zz = zz_s[row];
#pragma unroll
        for (int c = 0; c < 8; ++c) {
          int k = kt * KT + 16 * c + l15;
          float dv = (zz - acc[m][c][rg] * ACC_SCL) + ccv[c];
          if (dv <= th) {
            int idx = atomicAdd(&emit_cnt, 1);
            if (idx < EMIT_CAP) emit_s[idx] = ((unsigned)row << 10) | (unsigned)k;
          }
        }
      }
    // next kt's in-loop barriers separate emission from further rowmin updates
  }

  // ---- exact recheck of candidates: reproduces exact fp32 bits ----
  __syncthreads();
  int cnt = emit_cnt;
  bool over = cnt > EMIT_CAP;
  if (t < RT) rowmin_s[t] = 0xFFFFFFFFu;
  __syncthreads();

  if (!over) {
    unsigned mydd[16]; int myn[16], myk[16]; int mc = 0;
    for (int p = t; p < cnt; p += 256) {
      unsigned e = emit_s[p];
      int n = (int)(e >> 10), k = (int)(e & 1023);
      const float* zp = z + (rowbase + n) * DIM;
      const float* cp = cb + (long)k * DIM;
      float dot = 0.f;
      for (int d = 0; d < DIM; d += 4) {   // sequential fmaf chain, d ascending
        float4 zv = *(const float4*)(zp + d);
        float4 cv = *(const float4*)(cp + d);
        dot = fmaf(zv.x, cv.x, dot); dot = fmaf(zv.y, cv.y, dot);
        dot = fmaf(zv.z, cv.z, dot); dot = fmaf(zv.w, cv.w, dot);
      }
      float dd = (zz_s[n] - 2.0f * dot) + cc_g[k];
      mydd[mc] = __float_as_uint(dd); myn[mc] = n; myk[mc] = k; ++mc;
      atomicMin(&rowmin_s[n], __float_as_uint(dd));
    }
    __syncthreads();
    for (int i = 0; i < mc; ++i)
      if (mydd[i] == rowmin_s[myn[i]]) atomicMin(&kmin_s[myn[i]], myk[i]);
  } else {
    // pathological overflow fallback (never expected): exact full scan
    for (int p = t; p < RT * KCB; p += 256) {
      int n = p >> 10, k = p & 1023;
      const float* zp = z + (rowbase + n) * DIM;
      const float* cp = cb + (long)k * DIM;
      float dot = 0.f;
      for (int d = 0; d < DIM; d += 4) {
        float4 zv = *(const float4*)(zp + d);
        float4 cv = *(const float4*)(cp + d);
        dot = fmaf(zv.x, cv.x, dot); dot = fmaf(zv.y, cv.y, dot);
        dot = fmaf(zv.z, cv.z, dot); dot = fmaf(zv.w, cv.w, dot);
      }
      float dd = (zz_s[n] - 2.0f * dot) + cc_g[k];
      atomicMin(&rowmin_s[n], __float_as_uint(dd));
    }
    __syncthreads();
    for (int p = t; p < RT * KCB; p += 256) {
      int n = p >> 10, k = p & 1023;
      const float* zp = z + (rowbase + n) * DIM;
      const float* cp = cb + (long)k * DIM;
      float dot = 0.f;
      for (int d = 0; d < DIM; d += 4) {
        float4 zv = *(const float4*)(zp + d);
        float4 cv = *(const float4*)(cp + d);
        dot = fmaf(zv.x, cv.x, dot); dot = fmaf(zv.y, cv.y, dot);
        dot = fmaf(zv.z, cv.z, dot); dot = fmaf(zv.w, cv.w, dot);
      }
      float dd = (zz_s[n] - 2.0f * dot) + cc_g[k];
      if (__float_as_uint(dd) == rowmin_s[n]) atomicMin(&kmin_s[n], k);
    }
  }
  __syncthreads();
  if (t < RT) ids_f[rowbase + t] = (float)kmin_s[t];
}

// K2: out0 = z, out1 = codebook[ids], fp64 partial sum of (zq - z)^2
__global__ void output_kernel(const float* __restrict__ z, const float* __restrict__ cb,
                              const float* __restrict__ ids_f,
                              float* __restrict__ out_z, float* __restrict__ out_zq,
                              double* __restrict__ loss_acc) {
  __shared__ double red[4];
  double acc = 0.0;
  const long total4 = (long)N_TOK * DIM / 4;
  long idx    = (long)blockIdx.x * blockDim.x + threadIdx.x;
  long stride = (long)gridDim.x * blockDim.x;
  for (long i = idx; i < total4; i += stride) {
    long e = i * 4;
    long r = e >> 8;
    int  k = (int)ids_f[r];
    float4 vz = *(const float4*)(z + e);
    float4 vc = *(const float4*)(cb + (long)k * DIM + (e & 255));
    *(float4*)(out_z + e)  = vz;
    *(float4*)(out_zq + e) = vc;
    float d0 = vc.x - vz.x, d1 = vc.y - vz.y, d2 = vc.z - vz.z, d3 = vc.w - vz.w;
    acc += (double)(d0 * d0) + (double)(d1 * d1) + (double)(d2 * d2) + (double)(d3 * d3);
  }
#pragma unroll
  for (int off = 32; off > 0; off >>= 1) acc += __shfl_down(acc, off, 64);
  int lane = threadIdx.x & 63, wv = threadIdx.x >> 6;
  if (lane == 0) red[wv] = acc;
  __syncthreads();
  if (threadIdx.x == 0) {
    double s = (red[0] + red[1]) + (red[2] + red[3]);
    atomicAdd(loss_acc, s);
  }
}

// K3: loss = 1.25 * mean((zq - z)^2)
__global__ void finalize_kernel(const double* __restrict__ loss_acc,
                                float* __restrict__ out_loss) {
  if (threadIdx.x == 0) {
    double mean = *loss_acc / (double)((long)N_TOK * DIM);
    out_loss[0] = (float)(1.25 * mean);
  }
}

extern "C" void kernel_launch(void* const* d_in, const int* in_sizes, int n_in,
                              void* d_out, int out_size, void* d_ws, size_t ws_size,
                              hipStream_t stream) {
  const float* z  = (const float*)d_in[0];
  const float* cb = (const float*)d_in[1];
  float* out      = (float*)d_out;
  float* out_z    = out;                              // [N, D]
  float* out_zq   = out + (long)N_TOK * DIM;          // [N, D]
  float* out_ids  = out_zq + (long)N_TOK * DIM;       // [N] as fp32
  float* out_loss = out_ids + N_TOK;                  // [1]

  double* loss_acc = (double*)d_ws;                   // 8 B in ws

  // scratch inside the out_z region (dead until output_kernel overwrites it):
  // ch16 (512 KB) | cc (4 KB)  -- all consumed before K2 writes out_z
  short* ch_g = (short*)((char*)d_out);
  float* cc_g = (float*)((char*)d_out + 524288);

  prep_cc<<<4, 256, 0, stream>>>(cb, cc_g, loss_acc);
  prep_h16<<<KCB * DIM / 256, 256, 0, stream>>>(cb, ch_g);
  argmin_kernel<<<N_TOK / RT, 256, 0, stream>>>(z, cb, ch_g, cc_g, out_ids);
  output_kernel<<<2048, 256, 0, stream>>>(z, cb, out_ids, out_z, out_zq, loss_acc);
  finalize_kernel<<<1, 64, 0, stream>>>(loss_acc, out_loss);
}